// Round 1
// 608.647 us; speedup vs baseline: 1.1172x; 1.1172x over previous
//
#include <hip/hip_runtime.h>
#include <math.h>

// Problem dims
#define B_ 4
#define L_ 512
#define MROWS 2048
#define D_MODEL 384
#define N_LAYER 4
#define D_INNER 768
#define N_STATE 16
#define DT_RANK 24
#define D_CONV 4
#define VOCAB 1544
#define FEAT 1536
#define XPROJ_N 56
#define NCH 8               // scan chunks per batch (L/64)
#define SCH 64              // scan chunk length
#define DG 4                // d-channels per scan block

typedef __attribute__((ext_vector_type(8))) short short8;
typedef __attribute__((ext_vector_type(4))) float floatx4;

__device__ __forceinline__ float softplus_f(float x) { return x > 20.f ? x : log1pf(expf(x)); }
__device__ __forceinline__ float silu_f(float x) { return x / (1.f + __expf(-x)); }

// f32 -> bf16 (RNE), two packed into one u32
__device__ __forceinline__ unsigned pack2bf(float x, float y) {
    unsigned ux = __float_as_uint(x); ux = (ux + 0x7FFFu + ((ux >> 16) & 1u)) >> 16;
    unsigned uy = __float_as_uint(y); uy = (uy + 0x7FFFu + ((uy >> 16) & 1u)) >> 16;
    return ux | (uy << 16);
}

// DPP row-rotate add: x + (x rotated by N within each 16-lane row).
template <int CTRL>
__device__ __forceinline__ float dpp_radd(float x) {
    int r = __builtin_amdgcn_update_dpp(0, __float_as_int(x), CTRL, 0xf, 0xf, true);
    return x + __int_as_float(r);
}

__device__ __forceinline__ float4 ld4_guard(const float* __restrict__ p, int k, int ke) {
    if (k + 3 < ke) return *(const float4*)(p + k);
    float4 r = make_float4(0.f, 0.f, 0.f, 0.f);
    if (k + 0 < ke) r.x = p[k + 0];
    if (k + 1 < ke) r.y = p[k + 1];
    if (k + 2 < ke) r.z = p[k + 2];
    return r;
}

__device__ __forceinline__ short8 ld8h_guard(const short* __restrict__ p, int k, int ke) {
    if (k + 7 < ke) return *(const short8*)(p + k);
    short8 r = {0, 0, 0, 0, 0, 0, 0, 0};
#pragma unroll
    for (int j = 0; j < 8; ++j)
        if (k + j < ke) r[j] = p[k + j];
    return r;
}

// ---------------------------------------------------------------------------
// One-shot weight/input cast f32 -> bf16 + grid-stride zeroing of atomic dsts.
// Segments: fc_W, in_proj_W, x_proj_W, out_proj_W, head_W, input_ids.
// Zero tail covers x_ws + 4 per-layer xdbl buffers (contiguous).
// ---------------------------------------------------------------------------
struct CastDesc {
    const float* src[6];
    short*       dst[6];
    unsigned     cum[6];   // exclusive prefix ends, in float4 units
};

__global__ __launch_bounds__(256) void cast_w_k(CastDesc cd, unsigned total4,
                                                float4* __restrict__ zb, unsigned z4)
{
    unsigned i = blockIdx.x * 256 + threadIdx.x;
    if (i < total4) {
        int s = 0;
#pragma unroll
        for (int j = 0; j < 5; ++j)
            if (i >= cd.cum[j] && s == j) s = j + 1;
        unsigned off = i - (s ? cd.cum[s - 1] : 0u);
        float4 v = ((const float4*)cd.src[s])[off];
        uint2 pk;
        pk.x = pack2bf(v.x, v.y);
        pk.y = pack2bf(v.z, v.w);
        ((uint2*)cd.dst[s])[off] = pk;
    } else {
        unsigned zi = i - total4;
        if (zi < z4) zb[zi] = make_float4(0.f, 0.f, 0.f, 0.f);
    }
}

// ---------------------------------------------------------------------------
// MFMA bf16 GEMM: C[m,n] (+)= sum_k A[m,k]*W[n,k].  W pre-cast bf16.
// Pipelined K-loop: stage(k+1) -> prefetch(k+2) -> MFMA(k) -> barrier.
// ABF: A pre-cast bf16. EPI: 0 none, 1 +bias(z==0 if ATOMIC), 2 softplus+bias.
// ---------------------------------------------------------------------------
#define ASTR 40

template <int EPI, bool GATED, bool ATOMIC, bool RMSN, bool NG, bool ABF>
__global__ __launch_bounds__(256) void mfma_gemm(
    const float* __restrict__ A, const short* __restrict__ Abf,
    const short* __restrict__ Wb,
    const float* __restrict__ bias, const float* __restrict__ gate,
    const float* __restrict__ nw,
    float* __restrict__ C, int M, int N, int K, int lda, int ldg, int ldc, int KC)
{
    __shared__ short As[2][64 * ASTR];
    __shared__ short Ws[2][64 * ASTR];
    __shared__ float sscale[64];

    const int t  = threadIdx.x;
    const int m0 = blockIdx.y * 64;
    const int n0 = blockIdx.x * 64;
    const int ks = blockIdx.z * KC;
    const int ke = min(K, ks + KC);

    const int srow = t >> 2;           // 0..63
    const int sseg = (t & 3) * 8;      // 0,8,16,24

    if (RMSN) {
        const int row = t >> 2, q = t & 3;
        const float* xr = A + (size_t)(m0 + row) * lda + q * (K >> 2);
        float s = 0.f;
        for (int i = 0; i < (K >> 2); i += 4) {
            float4 v = *(const float4*)(xr + i);
            s += v.x * v.x + v.y * v.y + v.z * v.z + v.w * v.w;
        }
        s += __shfl_xor(s, 1, 64);
        s += __shfl_xor(s, 2, 64);
        if (q == 0) sscale[row] = rsqrtf(s / (float)K + 1e-5f);
        __syncthreads();
    }

    float4 ra0, ra1, rg0, rg1, rn0, rn1;
    short8 ra8, rw8;

    auto prefetch = [&](int k0) {
        if (ABF) {
            ra8 = ld8h_guard(Abf + (size_t)(m0 + srow) * lda, k0 + sseg, ke);
        } else {
            const float* ar = A + (size_t)(m0 + srow) * lda;
            ra0 = ld4_guard(ar, k0 + sseg, ke);
            ra1 = ld4_guard(ar, k0 + sseg + 4, ke);
            if (GATED) {
                const float* gr = gate + (size_t)(m0 + srow) * ldg;
                rg0 = ld4_guard(gr, k0 + sseg, ke);
                rg1 = ld4_guard(gr, k0 + sseg + 4, ke);
            }
            if (RMSN) {
                rn0 = ld4_guard(nw, k0 + sseg, ke);
                rn1 = ld4_guard(nw, k0 + sseg + 4, ke);
            }
        }
        if (!NG || (n0 + srow) < N) {
            rw8 = ld8h_guard(Wb + (size_t)(n0 + srow) * (size_t)K, k0 + sseg, ke);
        } else {
            rw8 = (short8){0, 0, 0, 0, 0, 0, 0, 0};
        }
    };

    auto stage = [&](int p) {
        if (ABF) {
            *(short8*)&As[p][srow * ASTR + sseg] = ra8;
        } else {
            float4 a0 = ra0, a1 = ra1;
            if (GATED) {
                a0.x *= silu_f(rg0.x); a0.y *= silu_f(rg0.y); a0.z *= silu_f(rg0.z); a0.w *= silu_f(rg0.w);
                a1.x *= silu_f(rg1.x); a1.y *= silu_f(rg1.y); a1.z *= silu_f(rg1.z); a1.w *= silu_f(rg1.w);
            }
            if (RMSN) {
                float sc = sscale[srow];
                a0.x *= sc * rn0.x; a0.y *= sc * rn0.y; a0.z *= sc * rn0.z; a0.w *= sc * rn0.w;
                a1.x *= sc * rn1.x; a1.y *= sc * rn1.y; a1.z *= sc * rn1.z; a1.w *= sc * rn1.w;
            }
            int4 pa;
            pa.x = pack2bf(a0.x, a0.y); pa.y = pack2bf(a0.z, a0.w);
            pa.z = pack2bf(a1.x, a1.y); pa.w = pack2bf(a1.z, a1.w);
            *(int4*)&As[p][srow * ASTR + sseg] = pa;
        }
        *(short8*)&Ws[p][srow * ASTR + sseg] = rw8;
    };

    prefetch(ks);
    stage(0);
    if (ks + 32 < ke) prefetch(ks + 32);   // loads for iter 2 in flight across barrier
    __syncthreads();

    floatx4 acc[2][2];
#pragma unroll
    for (int i = 0; i < 2; ++i)
#pragma unroll
        for (int j = 0; j < 2; ++j) acc[i][j] = (floatx4){0.f, 0.f, 0.f, 0.f};

    const int w    = t >> 6;
    const int lane = t & 63;
    const int quad = lane >> 4;
    const int lm   = lane & 15;
    const int aoff = ((w >> 1) * 32 + lm) * ASTR + quad * 8;
    const int boff = ((w & 1) * 32 + lm) * ASTR + quad * 8;

    int p = 0;
    for (int k0 = ks; k0 < ke; k0 += 32) {
        const bool more = (k0 + 32 < ke);
        if (more) {
            stage(p ^ 1);                       // consumes loads issued 1 iter ago
            if (k0 + 64 < ke) prefetch(k0 + 64); // issue 2 iters ahead
        }
        short8 a0 = *(const short8*)&As[p][aoff];
        short8 a1 = *(const short8*)&As[p][aoff + 16 * ASTR];
        short8 b0 = *(const short8*)&Ws[p][boff];
        short8 b1 = *(const short8*)&Ws[p][boff + 16 * ASTR];
        acc[0][0] = __builtin_amdgcn_mfma_f32_16x16x32_bf16(a0, b0, acc[0][0], 0, 0, 0);
        acc[0][1] = __builtin_amdgcn_mfma_f32_16x16x32_bf16(a0, b1, acc[0][1], 0, 0, 0);
        acc[1][0] = __builtin_amdgcn_mfma_f32_16x16x32_bf16(a1, b0, acc[1][0], 0, 0, 0);
        acc[1][1] = __builtin_amdgcn_mfma_f32_16x16x32_bf16(a1, b1, acc[1][1], 0, 0, 0);
        if (more) {
            __syncthreads();
            p ^= 1;
        }
    }

    const int rbase = m0 + (w >> 1) * 32 + quad * 4;
    const int cbase = n0 + (w & 1) * 32 + lm;
#pragma unroll
    for (int mt = 0; mt < 2; ++mt)
#pragma unroll
        for (int nt = 0; nt < 2; ++nt) {
            const int gc = cbase + nt * 16;
            if (NG && gc >= N) continue;
#pragma unroll
            for (int r = 0; r < 4; ++r) {
                const size_t gr = rbase + mt * 16 + r;
                float v = acc[mt][nt][r];
                if (ATOMIC) {
                    if (EPI == 1 && blockIdx.z == 0) v += bias[gc];
                    atomicAdd(&C[gr * ldc + gc], v);
                } else {
                    if (EPI == 1) v += bias[gc];
                    if (EPI == 2) v = softplus_f(v + bias[gc]);
                    C[gr * ldc + gc] = v;
                }
            }
        }
}

// ---------------------------------------------------------------------------
// Depthwise causal conv (width 4) + bias + SiLU; writes u (f32) and u_bf.
// ---------------------------------------------------------------------------
__global__ __launch_bounds__(256) void conv_silu_k(
    const float* __restrict__ xz, const float* __restrict__ w,
    const float* __restrict__ cb, float* __restrict__ u, short* __restrict__ ubf)
{
    int idx = blockIdx.x * 256 + threadIdx.x;
    if (idx >= MROWS * (D_INNER / 4)) return;
    int dq = idx % (D_INNER / 4);
    int m  = idx / (D_INNER / 4);
    int d0 = dq * 4;
    int b = m / L_, l = m % L_;
    float4 wq[4];
#pragma unroll
    for (int j = 0; j < 4; ++j) wq[j] = *(const float4*)(w + (d0 + j) * D_CONV);
    float acc[4];
#pragma unroll
    for (int j = 0; j < 4; ++j) acc[j] = cb[d0 + j];
#pragma unroll
    for (int tt = 0; tt < 4; ++tt) {
        int ll = l - 3 + tt;
        if (ll >= 0) {
            float4 xv = *(const float4*)(xz + (size_t)(b * L_ + ll) * (2 * D_INNER) + d0);
            acc[0] = fmaf(xv.x, ((const float*)&wq[0])[tt], acc[0]);
            acc[1] = fmaf(xv.y, ((const float*)&wq[1])[tt], acc[1]);
            acc[2] = fmaf(xv.z, ((const float*)&wq[2])[tt], acc[2]);
            acc[3] = fmaf(xv.w, ((const float*)&wq[3])[tt], acc[3]);
        }
    }
    float4 o = make_float4(silu_f(acc[0]), silu_f(acc[1]), silu_f(acc[2]), silu_f(acc[3]));
    *(float4*)(u + (size_t)m * D_INNER + d0) = o;
    uint2 pk;
    pk.x = pack2bf(o.x, o.y);
    pk.y = pack2bf(o.z, o.w);
    *(uint2*)(ubf + (size_t)m * D_INNER + d0) = pk;
}

// ---------------------------------------------------------------------------
// Fused selective scan:
//   phase 0: delta = softplus(xdbl[:, :24] @ dtW.T + dtb)  (f32 VALU)  + u staging
//   phase A: per-chunk local scan (wave c == chunk c), P/H to LDS
//   phase B: carry-in fix for chunks 1..7 from LDS P/H
//   phase C: y_final = (y_local + corr) * silu(res) -> bf16 write (GEMM-A ready)
// One block = all 8 chunks of (batch b, 4 d-channels).  512 threads,
// t = c*64 + dl*16 + n.  B/C streamed from global with 1-ahead prefetch.
// ---------------------------------------------------------------------------
__global__ __launch_bounds__(512, 2) void scan_fused_k(
    const float* __restrict__ xdbl, const float* __restrict__ u,
    const float* __restrict__ xz,
    const float* __restrict__ dtW, const float* __restrict__ dtb,
    const float* __restrict__ A_log, const float* __restrict__ Dp,
    short* __restrict__ ybf)
{
    __shared__ __align__(16) float sd[NCH][SCH][DG];
    __shared__ __align__(16) float su[NCH][SCH][DG];
    __shared__ __align__(16) float sy[NCH][SCH][DG];
    __shared__ float sP[NCH][DG][16], sH[NCH][DG][16];

    const int t  = threadIdx.x;
    const int c  = t >> 6;          // chunk == wave
    const int dl = (t >> 4) & 3;
    const int n  = t & 15;
    const int lt = t & 63;
    const int d0 = blockIdx.x * DG;
    const int d  = d0 + dl;
    const int b  = blockIdx.y;
    const size_t rbase = (size_t)b * L_ + c * SCH;

    // ---- phase 0: stage u; compute delta in f32 ----
    *(float4*)&su[c][lt][0] = *(const float4*)(u + (rbase + lt) * D_INNER + d0);

    {
        float4 w4[6];
#pragma unroll
        for (int q = 0; q < 6; ++q) w4[q] = *(const float4*)(dtW + (size_t)d * DT_RANK + q * 4);
        const float bias = dtb[d];
#pragma unroll
        for (int k = 0; k < 4; ++k) {
            const float* xr = xdbl + (rbase + n * 4 + k) * XPROJ_N;
            float acc = bias;
#pragma unroll
            for (int q = 0; q < 6; ++q) {
                float4 xv = *(const float4*)(xr + q * 4);
                acc = fmaf(xv.x, ((const float*)&w4[q])[0], acc);
                acc = fmaf(xv.y, ((const float*)&w4[q])[1], acc);
                acc = fmaf(xv.z, ((const float*)&w4[q])[2], acc);
                acc = fmaf(xv.w, ((const float*)&w4[q])[3], acc);
            }
            sd[c][n * 4 + k][dl] = softplus_f(acc);
        }
    }
    __syncthreads();

    // ---- phase A: local scan over own chunk ----
    const float Av = -expf(A_log[d * N_STATE + n]);
    const float Dd = Dp[d];
    const float* xb = xdbl + rbase * XPROJ_N;

    float h = 0.f, pacc = 1.f;
    float bB = xb[DT_RANK + n];
    float bC = xb[DT_RANK + N_STATE + n];
#pragma unroll 4
    for (int j = 0; j < SCH; ++j) {
        float nB = 0.f, nC = 0.f;
        if (j + 1 < SCH) {
            nB = xb[(j + 1) * XPROJ_N + DT_RANK + n];
            nC = xb[(j + 1) * XPROJ_N + DT_RANK + N_STATE + n];
        }
        float dv = sd[c][j][dl];
        float uv = su[c][j][dl];
        float e  = __expf(dv * Av);
        h = fmaf(e, h, dv * uv * bB);
        pacc *= e;
        float p = h * bC;
        p = dpp_radd<0x128>(p);
        p = dpp_radd<0x124>(p);
        p = dpp_radd<0x122>(p);
        p = dpp_radd<0x121>(p);
        if (n == 0) sy[c][j][dl] = fmaf(uv, Dd, p);
        bB = nB; bC = nC;
    }
    sP[c][dl][n] = pacc;
    sH[c][dl][n] = h;
    __syncthreads();

    // ---- phase B: carry-in correction for chunks 1..7 ----
    if (c > 0) {
        float hs = 0.f;
        for (int s = 0; s < c; ++s)
            hs = fmaf(sP[s][dl][n], hs, sH[s][dl][n]);
        float g  = hs;
        float cC = xb[DT_RANK + N_STATE + n];
#pragma unroll 4
        for (int j = 0; j < SCH; ++j) {
            float nC2 = 0.f;
            if (j + 1 < SCH) nC2 = xb[(j + 1) * XPROJ_N + DT_RANK + N_STATE + n];
            float dv = sd[c][j][dl];
            g *= __expf(dv * Av);
            float p = g * cC;
            p = dpp_radd<0x128>(p);
            p = dpp_radd<0x124>(p);
            p = dpp_radd<0x122>(p);
            p = dpp_radd<0x121>(p);
            if (n == 0) sy[c][j][dl] += p;
            cC = nC2;
        }
    }
    __syncthreads();

    // ---- phase C: gate with silu(res) and emit bf16 ----
    {
        const size_t row = rbase + lt;
        float4 rv = *(const float4*)(xz + row * (2 * D_INNER) + D_INNER + d0);
        float4 yv = *(const float4*)&sy[c][lt][0];
        float o0 = yv.x * silu_f(rv.x);
        float o1 = yv.y * silu_f(rv.y);
        float o2 = yv.z * silu_f(rv.z);
        float o3 = yv.w * silu_f(rv.w);
        uint2 pk;
        pk.x = pack2bf(o0, o1);
        pk.y = pack2bf(o2, o3);
        *(uint2*)(ybf + row * D_INNER + d0) = pk;
    }
}

// ---------------------------------------------------------------------------
extern "C" void kernel_launch(void* const* d_in, const int* in_sizes, int n_in,
                              void* d_out, int out_size, void* d_ws, size_t ws_size,
                              hipStream_t stream)
{
    const float* input_ids = (const float*)d_in[0];
    const float* fc_W      = (const float*)d_in[1];
    const float* fc_b      = (const float*)d_in[2];
    const float* in_proj_W = (const float*)d_in[3];
    const float* conv_W    = (const float*)d_in[4];
    const float* conv_b    = (const float*)d_in[5];
    const float* x_proj_W  = (const float*)d_in[6];
    const float* dt_proj_W = (const float*)d_in[7];
    const float* dt_proj_b = (const float*)d_in[8];
    const float* A_log     = (const float*)d_in[9];
    const float* Dp        = (const float*)d_in[10];
    const float* out_proj_W= (const float*)d_in[11];
    const float* norm_W    = (const float*)d_in[12];
    const float* normf_W   = (const float*)d_in[13];
    const float* head_W    = (const float*)d_in[14];
    float* out = (float*)d_out;

    float* ws       = (float*)d_ws;
    // f32 region: x_ws + per-layer xdbl contiguous (single zero span), then xz, u.
    float* x_ws     = ws;                                        // M*384
    float* xdbl_ws  = x_ws    + (size_t)MROWS * D_MODEL;         // 4 * M*56
    float* xz_ws    = xdbl_ws + (size_t)N_LAYER * MROWS * XPROJ_N; // M*1536
    float* u_ws     = xz_ws   + (size_t)MROWS * 2 * D_INNER;     // M*768
    // bf16 region
    short* bf       = (short*)(u_ws + (size_t)MROWS * D_INNER);
    short* wbf_fc   = bf;
    short* wbf_in   = wbf_fc  + (size_t)D_MODEL * VOCAB;
    short* wbf_x    = wbf_in  + (size_t)N_LAYER * 2 * D_INNER * D_MODEL;
    short* wbf_out  = wbf_x   + (size_t)N_LAYER * XPROJ_N * D_INNER;
    short* wbf_head = wbf_out + (size_t)N_LAYER * D_MODEL * D_INNER;
    short* ids_bf   = wbf_head+ (size_t)FEAT * D_MODEL;
    short* ubf_ws   = ids_bf  + (size_t)MROWS * VOCAB;
    short* ybf_ws   = ubf_ws  + (size_t)MROWS * D_INNER;

    const dim3 blk(256);
    const dim3 blk512(512);

    // --- one-shot cast to bf16 (weights + input_ids) + zero atomic dst buffers ---
    CastDesc cd;
    cd.src[0] = fc_W;       cd.dst[0] = wbf_fc;
    cd.src[1] = in_proj_W;  cd.dst[1] = wbf_in;
    cd.src[2] = x_proj_W;   cd.dst[2] = wbf_x;
    cd.src[3] = out_proj_W; cd.dst[3] = wbf_out;
    cd.src[4] = head_W;     cd.dst[4] = wbf_head;
    cd.src[5] = input_ids;  cd.dst[5] = ids_bf;
    unsigned c0 = (unsigned)(D_MODEL * VOCAB / 4);
    unsigned c1 = c0 + (unsigned)(N_LAYER * 2 * D_INNER * D_MODEL / 4);
    unsigned c2 = c1 + (unsigned)(N_LAYER * XPROJ_N * D_INNER / 4);
    unsigned c3 = c2 + (unsigned)(N_LAYER * D_MODEL * D_INNER / 4);
    unsigned c4 = c3 + (unsigned)(FEAT * D_MODEL / 4);
    unsigned c5 = c4 + (unsigned)(MROWS * VOCAB / 4);
    cd.cum[0] = c0; cd.cum[1] = c1; cd.cum[2] = c2;
    cd.cum[3] = c3; cd.cum[4] = c4; cd.cum[5] = c5;
    const unsigned zero4 = (unsigned)((MROWS * D_MODEL + N_LAYER * MROWS * XPROJ_N) / 4);
    cast_w_k<<<(c5 + zero4 + 255) / 256, blk, 0, stream>>>(cd, c5, (float4*)x_ws, zero4);

    // x = input_ids @ fc_W.T + fc_b   (A pre-cast bf16, split-K=7, atomic)
    mfma_gemm<1, false, true, false, false, true><<<dim3(D_MODEL / 64, MROWS / 64, 7), blk, 0, stream>>>(
        nullptr, ids_bf, wbf_fc, fc_b, nullptr, nullptr, x_ws,
        MROWS, D_MODEL, VOCAB, VOCAB, 0, D_MODEL, 256);

    for (int i = 0; i < N_LAYER; ++i) {
        float* xdbl_i = xdbl_ws + (size_t)i * MROWS * XPROJ_N;

        // xz = rmsnorm(x, norm_W) @ in_proj_W.T   (rmsnorm fused into A staging)
        mfma_gemm<0, false, false, true, false, false><<<dim3(2 * D_INNER / 64, MROWS / 64, 1), blk, 0, stream>>>(
            x_ws, nullptr, wbf_in + (size_t)i * 2 * D_INNER * D_MODEL,
            nullptr, nullptr, norm_W + i * D_MODEL, xz_ws,
            MROWS, 2 * D_INNER, D_MODEL, D_MODEL, 0, 2 * D_INNER, D_MODEL);

        // u = silu(conv(xz[:, :768]) + conv_b)  (f32 + bf16 copies)
        conv_silu_k<<<(MROWS * (D_INNER / 4) + 255) / 256, blk, 0, stream>>>(
            xz_ws, conv_W + (size_t)i * D_INNER * D_CONV, conv_b + i * D_INNER,
            u_ws, ubf_ws);

        // x_dbl = u @ x_proj_W[i].T  (A pre-cast bf16, N=56 guarded, split-K=6,
        // dst pre-zeroed once in cast_w_k -- per-layer buffer)
        mfma_gemm<0, false, true, false, true, true><<<dim3(1, MROWS / 64, 6), blk, 0, stream>>>(
            nullptr, ubf_ws, wbf_x + (size_t)i * XPROJ_N * D_INNER,
            nullptr, nullptr, nullptr, xdbl_i,
            MROWS, XPROJ_N, D_INNER, D_INNER, 0, XPROJ_N, 128);

        // fused: dt_proj+softplus -> two-phase chunked scan -> gate -> ybf (bf16)
        scan_fused_k<<<dim3(D_INNER / DG, B_), blk512, 0, stream>>>(
            xdbl_i, u_ws, xz_ws,
            dt_proj_W + (size_t)i * D_INNER * DT_RANK, dt_proj_b + i * D_INNER,
            A_log + (size_t)i * D_INNER * N_STATE, Dp + i * D_INNER, ybf_ws);

        // x += ybf @ out_proj_W.T  (A pre-cast bf16 gated y, split-K=2, atomic residual)
        mfma_gemm<0, false, true, false, false, true><<<dim3(D_MODEL / 64, MROWS / 64, 2), blk, 0, stream>>>(
            nullptr, ybf_ws, wbf_out + (size_t)i * D_MODEL * D_INNER,
            nullptr, nullptr, nullptr, x_ws,
            MROWS, D_MODEL, D_INNER, D_INNER, 0, D_MODEL, 384);
    }

    // out = rmsnorm(x, normf_W) @ head_W.T  (rmsnorm fused)
    mfma_gemm<0, false, false, true, false, false><<<dim3(FEAT / 64, MROWS / 64, 1), blk, 0, stream>>>(
        x_ws, nullptr, wbf_head, nullptr, nullptr, normf_W, out,
        MROWS, FEAT, D_MODEL, D_MODEL, 0, FEAT, D_MODEL);
}

// Round 2
// 565.910 us; speedup vs baseline: 1.2016x; 1.0755x over previous
//
#include <hip/hip_runtime.h>
#include <math.h>

// Problem dims
#define B_ 4
#define L_ 512
#define MROWS 2048
#define D_MODEL 384
#define N_LAYER 4
#define D_INNER 768
#define N_STATE 16
#define DT_RANK 24
#define D_CONV 4
#define VOCAB 1544
#define FEAT 1536
#define XPROJ_N 56
#define NCH 8               // scan chunks per batch (L/64)
#define SCH 64              // scan chunk length
#define DG 4                // d-channels per scan block

typedef __attribute__((ext_vector_type(8))) short short8;
typedef __attribute__((ext_vector_type(4))) float floatx4;

__device__ __forceinline__ float softplus_f(float x) { return x > 20.f ? x : log1pf(expf(x)); }
__device__ __forceinline__ float silu_f(float x) { return x / (1.f + __expf(-x)); }

// f32 -> bf16 (RNE), two packed into one u32
__device__ __forceinline__ unsigned pack2bf(float x, float y) {
    unsigned ux = __float_as_uint(x); ux = (ux + 0x7FFFu + ((ux >> 16) & 1u)) >> 16;
    unsigned uy = __float_as_uint(y); uy = (uy + 0x7FFFu + ((uy >> 16) & 1u)) >> 16;
    return ux | (uy << 16);
}

// DPP row-rotate add: x + (x rotated by N within each 16-lane row).
template <int CTRL>
__device__ __forceinline__ float dpp_radd(float x) {
    int r = __builtin_amdgcn_update_dpp(0, __float_as_int(x), CTRL, 0xf, 0xf, true);
    return x + __int_as_float(r);
}

__device__ __forceinline__ float4 ld4_guard(const float* __restrict__ p, int k, int ke) {
    if (k + 3 < ke) return *(const float4*)(p + k);
    float4 r = make_float4(0.f, 0.f, 0.f, 0.f);
    if (k + 0 < ke) r.x = p[k + 0];
    if (k + 1 < ke) r.y = p[k + 1];
    if (k + 2 < ke) r.z = p[k + 2];
    return r;
}

__device__ __forceinline__ short8 ld8h_guard(const short* __restrict__ p, int k, int ke) {
    if (k + 7 < ke) return *(const short8*)(p + k);
    short8 r = {0, 0, 0, 0, 0, 0, 0, 0};
#pragma unroll
    for (int j = 0; j < 8; ++j)
        if (k + j < ke) r[j] = p[k + j];
    return r;
}

// ---------------------------------------------------------------------------
// One-shot weight/input cast f32 -> bf16 + grid-stride zeroing of atomic dsts.
// Segments: fc_W, in_proj_W, x_proj_W, out_proj_W, head_W, input_ids.
// Zero tail covers x_ws + 4 per-layer xdbl buffers (contiguous).
// ---------------------------------------------------------------------------
struct CastDesc {
    const float* src[6];
    short*       dst[6];
    unsigned     cum[6];   // exclusive prefix ends, in float4 units
};

__global__ __launch_bounds__(256) void cast_w_k(CastDesc cd, unsigned total4,
                                                float4* __restrict__ zb, unsigned z4)
{
    unsigned i = blockIdx.x * 256 + threadIdx.x;
    if (i < total4) {
        int s = 0;
#pragma unroll
        for (int j = 0; j < 5; ++j)
            if (i >= cd.cum[j] && s == j) s = j + 1;
        unsigned off = i - (s ? cd.cum[s - 1] : 0u);
        float4 v = ((const float4*)cd.src[s])[off];
        uint2 pk;
        pk.x = pack2bf(v.x, v.y);
        pk.y = pack2bf(v.z, v.w);
        ((uint2*)cd.dst[s])[off] = pk;
    } else {
        unsigned zi = i - total4;
        if (zi < z4) zb[zi] = make_float4(0.f, 0.f, 0.f, 0.f);
    }
}

// ---------------------------------------------------------------------------
// MFMA bf16 GEMM: C[m,n] (+)= sum_k A[m,k]*W[n,k].  W pre-cast bf16.
// Pipelined K-loop: stage(k+1) -> prefetch(k+2) -> MFMA(k) -> barrier.
// ABF: A pre-cast bf16. EPI: 0 none, 1 +bias(z==0 if ATOMIC), 2 softplus+bias.
// ---------------------------------------------------------------------------
#define ASTR 40

template <int EPI, bool GATED, bool ATOMIC, bool RMSN, bool NG, bool ABF>
__global__ __launch_bounds__(256) void mfma_gemm(
    const float* __restrict__ A, const short* __restrict__ Abf,
    const short* __restrict__ Wb,
    const float* __restrict__ bias, const float* __restrict__ gate,
    const float* __restrict__ nw,
    float* __restrict__ C, int M, int N, int K, int lda, int ldg, int ldc, int KC)
{
    __shared__ short As[2][64 * ASTR];
    __shared__ short Ws[2][64 * ASTR];
    __shared__ float sscale[64];

    const int t  = threadIdx.x;
    const int m0 = blockIdx.y * 64;
    const int n0 = blockIdx.x * 64;
    const int ks = blockIdx.z * KC;
    const int ke = min(K, ks + KC);

    const int srow = t >> 2;           // 0..63
    const int sseg = (t & 3) * 8;      // 0,8,16,24

    if (RMSN) {
        const int row = t >> 2, q = t & 3;
        const float* xr = A + (size_t)(m0 + row) * lda + q * (K >> 2);
        float s = 0.f;
        for (int i = 0; i < (K >> 2); i += 4) {
            float4 v = *(const float4*)(xr + i);
            s += v.x * v.x + v.y * v.y + v.z * v.z + v.w * v.w;
        }
        s += __shfl_xor(s, 1, 64);
        s += __shfl_xor(s, 2, 64);
        if (q == 0) sscale[row] = rsqrtf(s / (float)K + 1e-5f);
        __syncthreads();
    }

    float4 ra0, ra1, rg0, rg1, rn0, rn1;
    short8 ra8, rw8;

    auto prefetch = [&](int k0) {
        if (ABF) {
            ra8 = ld8h_guard(Abf + (size_t)(m0 + srow) * lda, k0 + sseg, ke);
        } else {
            const float* ar = A + (size_t)(m0 + srow) * lda;
            ra0 = ld4_guard(ar, k0 + sseg, ke);
            ra1 = ld4_guard(ar, k0 + sseg + 4, ke);
            if (GATED) {
                const float* gr = gate + (size_t)(m0 + srow) * ldg;
                rg0 = ld4_guard(gr, k0 + sseg, ke);
                rg1 = ld4_guard(gr, k0 + sseg + 4, ke);
            }
            if (RMSN) {
                rn0 = ld4_guard(nw, k0 + sseg, ke);
                rn1 = ld4_guard(nw, k0 + sseg + 4, ke);
            }
        }
        if (!NG || (n0 + srow) < N) {
            rw8 = ld8h_guard(Wb + (size_t)(n0 + srow) * (size_t)K, k0 + sseg, ke);
        } else {
            rw8 = (short8){0, 0, 0, 0, 0, 0, 0, 0};
        }
    };

    auto stage = [&](int p) {
        if (ABF) {
            *(short8*)&As[p][srow * ASTR + sseg] = ra8;
        } else {
            float4 a0 = ra0, a1 = ra1;
            if (GATED) {
                a0.x *= silu_f(rg0.x); a0.y *= silu_f(rg0.y); a0.z *= silu_f(rg0.z); a0.w *= silu_f(rg0.w);
                a1.x *= silu_f(rg1.x); a1.y *= silu_f(rg1.y); a1.z *= silu_f(rg1.z); a1.w *= silu_f(rg1.w);
            }
            if (RMSN) {
                float sc = sscale[srow];
                a0.x *= sc * rn0.x; a0.y *= sc * rn0.y; a0.z *= sc * rn0.z; a0.w *= sc * rn0.w;
                a1.x *= sc * rn1.x; a1.y *= sc * rn1.y; a1.z *= sc * rn1.z; a1.w *= sc * rn1.w;
            }
            int4 pa;
            pa.x = pack2bf(a0.x, a0.y); pa.y = pack2bf(a0.z, a0.w);
            pa.z = pack2bf(a1.x, a1.y); pa.w = pack2bf(a1.z, a1.w);
            *(int4*)&As[p][srow * ASTR + sseg] = pa;
        }
        *(short8*)&Ws[p][srow * ASTR + sseg] = rw8;
    };

    prefetch(ks);
    stage(0);
    if (ks + 32 < ke) prefetch(ks + 32);   // loads for iter 2 in flight across barrier
    __syncthreads();

    floatx4 acc[2][2];
#pragma unroll
    for (int i = 0; i < 2; ++i)
#pragma unroll
        for (int j = 0; j < 2; ++j) acc[i][j] = (floatx4){0.f, 0.f, 0.f, 0.f};

    const int w    = t >> 6;
    const int lane = t & 63;
    const int quad = lane >> 4;
    const int lm   = lane & 15;
    const int aoff = ((w >> 1) * 32 + lm) * ASTR + quad * 8;
    const int boff = ((w & 1) * 32 + lm) * ASTR + quad * 8;

    int p = 0;
    for (int k0 = ks; k0 < ke; k0 += 32) {
        const bool more = (k0 + 32 < ke);
        if (more) {
            stage(p ^ 1);                       // consumes loads issued 1 iter ago
            if (k0 + 64 < ke) prefetch(k0 + 64); // issue 2 iters ahead
        }
        short8 a0 = *(const short8*)&As[p][aoff];
        short8 a1 = *(const short8*)&As[p][aoff + 16 * ASTR];
        short8 b0 = *(const short8*)&Ws[p][boff];
        short8 b1 = *(const short8*)&Ws[p][boff + 16 * ASTR];
        acc[0][0] = __builtin_amdgcn_mfma_f32_16x16x32_bf16(a0, b0, acc[0][0], 0, 0, 0);
        acc[0][1] = __builtin_amdgcn_mfma_f32_16x16x32_bf16(a0, b1, acc[0][1], 0, 0, 0);
        acc[1][0] = __builtin_amdgcn_mfma_f32_16x16x32_bf16(a1, b0, acc[1][0], 0, 0, 0);
        acc[1][1] = __builtin_amdgcn_mfma_f32_16x16x32_bf16(a1, b1, acc[1][1], 0, 0, 0);
        if (more) {
            __syncthreads();
            p ^= 1;
        }
    }

    const int rbase = m0 + (w >> 1) * 32 + quad * 4;
    const int cbase = n0 + (w & 1) * 32 + lm;
#pragma unroll
    for (int mt = 0; mt < 2; ++mt)
#pragma unroll
        for (int nt = 0; nt < 2; ++nt) {
            const int gc = cbase + nt * 16;
            if (NG && gc >= N) continue;
#pragma unroll
            for (int r = 0; r < 4; ++r) {
                const size_t gr = rbase + mt * 16 + r;
                float v = acc[mt][nt][r];
                if (ATOMIC) {
                    if (EPI == 1 && blockIdx.z == 0) v += bias[gc];
                    atomicAdd(&C[gr * ldc + gc], v);
                } else {
                    if (EPI == 1) v += bias[gc];
                    if (EPI == 2) v = softplus_f(v + bias[gc]);
                    C[gr * ldc + gc] = v;
                }
            }
        }
}

// ---------------------------------------------------------------------------
// Depthwise causal conv (width 4) + bias + SiLU; writes u (f32) and u_bf.
// ---------------------------------------------------------------------------
__global__ __launch_bounds__(256) void conv_silu_k(
    const float* __restrict__ xz, const float* __restrict__ w,
    const float* __restrict__ cb, float* __restrict__ u, short* __restrict__ ubf)
{
    int idx = blockIdx.x * 256 + threadIdx.x;
    if (idx >= MROWS * (D_INNER / 4)) return;
    int dq = idx % (D_INNER / 4);
    int m  = idx / (D_INNER / 4);
    int d0 = dq * 4;
    int b = m / L_, l = m % L_;
    float4 wq[4];
#pragma unroll
    for (int j = 0; j < 4; ++j) wq[j] = *(const float4*)(w + (d0 + j) * D_CONV);
    float acc[4];
#pragma unroll
    for (int j = 0; j < 4; ++j) acc[j] = cb[d0 + j];
#pragma unroll
    for (int tt = 0; tt < 4; ++tt) {
        int ll = l - 3 + tt;
        if (ll >= 0) {
            float4 xv = *(const float4*)(xz + (size_t)(b * L_ + ll) * (2 * D_INNER) + d0);
            acc[0] = fmaf(xv.x, ((const float*)&wq[0])[tt], acc[0]);
            acc[1] = fmaf(xv.y, ((const float*)&wq[1])[tt], acc[1]);
            acc[2] = fmaf(xv.z, ((const float*)&wq[2])[tt], acc[2]);
            acc[3] = fmaf(xv.w, ((const float*)&wq[3])[tt], acc[3]);
        }
    }
    float4 o = make_float4(silu_f(acc[0]), silu_f(acc[1]), silu_f(acc[2]), silu_f(acc[3]));
    *(float4*)(u + (size_t)m * D_INNER + d0) = o;
    uint2 pk;
    pk.x = pack2bf(o.x, o.y);
    pk.y = pack2bf(o.z, o.w);
    *(uint2*)(ubf + (size_t)m * D_INNER + d0) = pk;
}

// ---------------------------------------------------------------------------
// Fused selective scan:
//   phase 0: delta = softplus(xdbl[:, :24] @ dtW.T + dtb)  (f32 VALU)  + u staging
//   phase A: per-chunk local scan (wave c == chunk c), P/H to LDS
//   phase B: carry-in fix for chunks 1..7 from LDS P/H
//   phase C: y_final = (y_local + corr) * silu(res) -> bf16 write (GEMM-A ready)
// One block = all 8 chunks of (batch b, 4 d-channels).  512 threads,
// t = c*64 + dl*16 + n.
// XCD-chunked blockIdx.x swizzle: gridDim.x=192 (%8==0), consecutive
// d-groups land on the SAME XCD so the 64B lines of u/xz/ybf (shared by 4
// adjacent d-groups) are fetched once per XCD instead of ~4x (r1: FETCH
// 51MB vs ~13MB unique, hbm 1.1TB/s, dur 58us).
// B/C loads: register double-buffered 4-deep prefetch (r1: 1-ahead scalar
// loads gave ~20cy cover vs ~200-400cy L2/L3 latency -> VALUBusy 42%).
// ---------------------------------------------------------------------------
__global__ __launch_bounds__(512, 2) void scan_fused_k(
    const float* __restrict__ xdbl, const float* __restrict__ u,
    const float* __restrict__ xz,
    const float* __restrict__ dtW, const float* __restrict__ dtb,
    const float* __restrict__ A_log, const float* __restrict__ Dp,
    short* __restrict__ ybf)
{
    __shared__ __align__(16) float sd[NCH][SCH][DG];
    __shared__ __align__(16) float su[NCH][SCH][DG];
    __shared__ __align__(16) float sy[NCH][SCH][DG];
    __shared__ float sP[NCH][DG][16], sH[NCH][DG][16];

    const int t  = threadIdx.x;
    const int c  = t >> 6;          // chunk == wave
    const int dl = (t >> 4) & 3;
    const int n  = t & 15;
    const int lt = t & 63;
    // XCD-chunked swizzle (bijective, 192 = 8 * 24)
    const int bx  = blockIdx.x;
    const int dgi = (bx & 7) * (D_INNER / DG / 8) + (bx >> 3);
    const int d0 = dgi * DG;
    const int d  = d0 + dl;
    const int b  = blockIdx.y;
    const size_t rbase = (size_t)b * L_ + c * SCH;

    // ---- phase 0: stage u; compute delta in f32 ----
    *(float4*)&su[c][lt][0] = *(const float4*)(u + (rbase + lt) * D_INNER + d0);

    {
        float4 w4[6];
#pragma unroll
        for (int q = 0; q < 6; ++q) w4[q] = *(const float4*)(dtW + (size_t)d * DT_RANK + q * 4);
        const float bias = dtb[d];
#pragma unroll
        for (int k = 0; k < 4; ++k) {
            const float* xr = xdbl + (rbase + n * 4 + k) * XPROJ_N;
            float acc = bias;
#pragma unroll
            for (int q = 0; q < 6; ++q) {
                float4 xv = *(const float4*)(xr + q * 4);
                acc = fmaf(xv.x, ((const float*)&w4[q])[0], acc);
                acc = fmaf(xv.y, ((const float*)&w4[q])[1], acc);
                acc = fmaf(xv.z, ((const float*)&w4[q])[2], acc);
                acc = fmaf(xv.w, ((const float*)&w4[q])[3], acc);
            }
            sd[c][n * 4 + k][dl] = softplus_f(acc);
        }
    }
    __syncthreads();

    // ---- phase A: local scan over own chunk ----
    const float Av = -expf(A_log[d * N_STATE + n]);
    const float Dd = Dp[d];
    const float* xbn = xdbl + rbase * XPROJ_N + DT_RANK + n;   // B: xbn[j*56], C: +16

    float h = 0.f, pacc = 1.f;
    float rB[4], rC[4];
#pragma unroll
    for (int jj = 0; jj < 4; ++jj) {
        rB[jj] = xbn[jj * XPROJ_N];
        rC[jj] = xbn[jj * XPROJ_N + N_STATE];
    }
#pragma unroll 2
    for (int g = 0; g < SCH / 4; ++g) {
        float nB[4] = {0.f, 0.f, 0.f, 0.f}, nC[4] = {0.f, 0.f, 0.f, 0.f};
        if (g + 1 < SCH / 4) {
#pragma unroll
            for (int jj = 0; jj < 4; ++jj) {
                nB[jj] = xbn[(g * 4 + 4 + jj) * XPROJ_N];
                nC[jj] = xbn[(g * 4 + 4 + jj) * XPROJ_N + N_STATE];
            }
        }
#pragma unroll
        for (int jj = 0; jj < 4; ++jj) {
            const int j = g * 4 + jj;
            float dv = sd[c][j][dl];
            float uv = su[c][j][dl];
            float e  = __expf(dv * Av);
            h = fmaf(e, h, dv * uv * rB[jj]);
            pacc *= e;
            float p = h * rC[jj];
            p = dpp_radd<0x128>(p);
            p = dpp_radd<0x124>(p);
            p = dpp_radd<0x122>(p);
            p = dpp_radd<0x121>(p);
            if (n == 0) sy[c][j][dl] = fmaf(uv, Dd, p);
        }
#pragma unroll
        for (int jj = 0; jj < 4; ++jj) { rB[jj] = nB[jj]; rC[jj] = nC[jj]; }
    }
    sP[c][dl][n] = pacc;
    sH[c][dl][n] = h;
    __syncthreads();

    // ---- phase B: carry-in correction for chunks 1..7 ----
    if (c > 0) {
        float hs = 0.f;
        for (int s = 0; s < c; ++s)
            hs = fmaf(sP[s][dl][n], hs, sH[s][dl][n]);
        float gv = hs;
        float rc2[4];
#pragma unroll
        for (int jj = 0; jj < 4; ++jj) rc2[jj] = xbn[jj * XPROJ_N + N_STATE];
#pragma unroll 2
        for (int gg = 0; gg < SCH / 4; ++gg) {
            float nc2[4] = {0.f, 0.f, 0.f, 0.f};
            if (gg + 1 < SCH / 4) {
#pragma unroll
                for (int jj = 0; jj < 4; ++jj)
                    nc2[jj] = xbn[(gg * 4 + 4 + jj) * XPROJ_N + N_STATE];
            }
#pragma unroll
            for (int jj = 0; jj < 4; ++jj) {
                const int j = gg * 4 + jj;
                float dv = sd[c][j][dl];
                gv *= __expf(dv * Av);
                float p = gv * rc2[jj];
                p = dpp_radd<0x128>(p);
                p = dpp_radd<0x124>(p);
                p = dpp_radd<0x122>(p);
                p = dpp_radd<0x121>(p);
                if (n == 0) sy[c][j][dl] += p;
            }
#pragma unroll
            for (int jj = 0; jj < 4; ++jj) rc2[jj] = nc2[jj];
        }
    }
    __syncthreads();

    // ---- phase C: gate with silu(res) and emit bf16 ----
    {
        const size_t row = rbase + lt;
        float4 rv = *(const float4*)(xz + row * (2 * D_INNER) + D_INNER + d0);
        float4 yv = *(const float4*)&sy[c][lt][0];
        float o0 = yv.x * silu_f(rv.x);
        float o1 = yv.y * silu_f(rv.y);
        float o2 = yv.z * silu_f(rv.z);
        float o3 = yv.w * silu_f(rv.w);
        uint2 pk;
        pk.x = pack2bf(o0, o1);
        pk.y = pack2bf(o2, o3);
        *(uint2*)(ybf + row * D_INNER + d0) = pk;
    }
}

// ---------------------------------------------------------------------------
extern "C" void kernel_launch(void* const* d_in, const int* in_sizes, int n_in,
                              void* d_out, int out_size, void* d_ws, size_t ws_size,
                              hipStream_t stream)
{
    const float* input_ids = (const float*)d_in[0];
    const float* fc_W      = (const float*)d_in[1];
    const float* fc_b      = (const float*)d_in[2];
    const float* in_proj_W = (const float*)d_in[3];
    const float* conv_W    = (const float*)d_in[4];
    const float* conv_b    = (const float*)d_in[5];
    const float* x_proj_W  = (const float*)d_in[6];
    const float* dt_proj_W = (const float*)d_in[7];
    const float* dt_proj_b = (const float*)d_in[8];
    const float* A_log     = (const float*)d_in[9];
    const float* Dp        = (const float*)d_in[10];
    const float* out_proj_W= (const float*)d_in[11];
    const float* norm_W    = (const float*)d_in[12];
    const float* normf_W   = (const float*)d_in[13];
    const float* head_W    = (const float*)d_in[14];
    float* out = (float*)d_out;

    float* ws       = (float*)d_ws;
    // f32 region: x_ws + per-layer xdbl contiguous (single zero span), then xz, u.
    float* x_ws     = ws;                                        // M*384
    float* xdbl_ws  = x_ws    + (size_t)MROWS * D_MODEL;         // 4 * M*56
    float* xz_ws    = xdbl_ws + (size_t)N_LAYER * MROWS * XPROJ_N; // M*1536
    float* u_ws     = xz_ws   + (size_t)MROWS * 2 * D_INNER;     // M*768
    // bf16 region
    short* bf       = (short*)(u_ws + (size_t)MROWS * D_INNER);
    short* wbf_fc   = bf;
    short* wbf_in   = wbf_fc  + (size_t)D_MODEL * VOCAB;
    short* wbf_x    = wbf_in  + (size_t)N_LAYER * 2 * D_INNER * D_MODEL;
    short* wbf_out  = wbf_x   + (size_t)N_LAYER * XPROJ_N * D_INNER;
    short* wbf_head = wbf_out + (size_t)N_LAYER * D_MODEL * D_INNER;
    short* ids_bf   = wbf_head+ (size_t)FEAT * D_MODEL;
    short* ubf_ws   = ids_bf  + (size_t)MROWS * VOCAB;
    short* ybf_ws   = ubf_ws  + (size_t)MROWS * D_INNER;

    const dim3 blk(256);
    const dim3 blk512(512);

    // --- one-shot cast to bf16 (weights + input_ids) + zero atomic dst buffers ---
    CastDesc cd;
    cd.src[0] = fc_W;       cd.dst[0] = wbf_fc;
    cd.src[1] = in_proj_W;  cd.dst[1] = wbf_in;
    cd.src[2] = x_proj_W;   cd.dst[2] = wbf_x;
    cd.src[3] = out_proj_W; cd.dst[3] = wbf_out;
    cd.src[4] = head_W;     cd.dst[4] = wbf_head;
    cd.src[5] = input_ids;  cd.dst[5] = ids_bf;
    unsigned c0 = (unsigned)(D_MODEL * VOCAB / 4);
    unsigned c1 = c0 + (unsigned)(N_LAYER * 2 * D_INNER * D_MODEL / 4);
    unsigned c2 = c1 + (unsigned)(N_LAYER * XPROJ_N * D_INNER / 4);
    unsigned c3 = c2 + (unsigned)(N_LAYER * D_MODEL * D_INNER / 4);
    unsigned c4 = c3 + (unsigned)(FEAT * D_MODEL / 4);
    unsigned c5 = c4 + (unsigned)(MROWS * VOCAB / 4);
    cd.cum[0] = c0; cd.cum[1] = c1; cd.cum[2] = c2;
    cd.cum[3] = c3; cd.cum[4] = c4; cd.cum[5] = c5;
    const unsigned zero4 = (unsigned)((MROWS * D_MODEL + N_LAYER * MROWS * XPROJ_N) / 4);
    cast_w_k<<<(c5 + zero4 + 255) / 256, blk, 0, stream>>>(cd, c5, (float4*)x_ws, zero4);

    // x = input_ids @ fc_W.T + fc_b   (A pre-cast bf16, split-K=7, atomic)
    mfma_gemm<1, false, true, false, false, true><<<dim3(D_MODEL / 64, MROWS / 64, 7), blk, 0, stream>>>(
        nullptr, ids_bf, wbf_fc, fc_b, nullptr, nullptr, x_ws,
        MROWS, D_MODEL, VOCAB, VOCAB, 0, D_MODEL, 256);

    for (int i = 0; i < N_LAYER; ++i) {
        float* xdbl_i = xdbl_ws + (size_t)i * MROWS * XPROJ_N;

        // xz = rmsnorm(x, norm_W) @ in_proj_W.T   (rmsnorm fused into A staging)
        mfma_gemm<0, false, false, true, false, false><<<dim3(2 * D_INNER / 64, MROWS / 64, 1), blk, 0, stream>>>(
            x_ws, nullptr, wbf_in + (size_t)i * 2 * D_INNER * D_MODEL,
            nullptr, nullptr, norm_W + i * D_MODEL, xz_ws,
            MROWS, 2 * D_INNER, D_MODEL, D_MODEL, 0, 2 * D_INNER, D_MODEL);

        // u = silu(conv(xz[:, :768]) + conv_b)  (f32 + bf16 copies)
        conv_silu_k<<<(MROWS * (D_INNER / 4) + 255) / 256, blk, 0, stream>>>(
            xz_ws, conv_W + (size_t)i * D_INNER * D_CONV, conv_b + i * D_INNER,
            u_ws, ubf_ws);

        // x_dbl = u @ x_proj_W[i].T  (A pre-cast bf16, N=56 guarded, split-K=6,
        // dst pre-zeroed once in cast_w_k -- per-layer buffer)
        mfma_gemm<0, false, true, false, true, true><<<dim3(1, MROWS / 64, 6), blk, 0, stream>>>(
            nullptr, ubf_ws, wbf_x + (size_t)i * XPROJ_N * D_INNER,
            nullptr, nullptr, nullptr, xdbl_i,
            MROWS, XPROJ_N, D_INNER, D_INNER, 0, XPROJ_N, 128);

        // fused: dt_proj+softplus -> two-phase chunked scan -> gate -> ybf (bf16)
        scan_fused_k<<<dim3(D_INNER / DG, B_), blk512, 0, stream>>>(
            xdbl_i, u_ws, xz_ws,
            dt_proj_W + (size_t)i * D_INNER * DT_RANK, dt_proj_b + i * D_INNER,
            A_log + (size_t)i * D_INNER * N_STATE, Dp + i * D_INNER, ybf_ws);

        // x += ybf @ out_proj_W.T  (A pre-cast bf16 gated y, split-K=2, atomic residual)
        mfma_gemm<0, false, true, false, false, true><<<dim3(D_MODEL / 64, MROWS / 64, 2), blk, 0, stream>>>(
            nullptr, ybf_ws, wbf_out + (size_t)i * D_MODEL * D_INNER,
            nullptr, nullptr, nullptr, x_ws,
            MROWS, D_MODEL, D_INNER, D_INNER, 0, D_MODEL, 384);
    }

    // out = rmsnorm(x, normf_W) @ head_W.T  (rmsnorm fused)
    mfma_gemm<0, false, false, true, false, false><<<dim3(FEAT / 64, MROWS / 64, 1), blk, 0, stream>>>(
        x_ws, nullptr, wbf_head, nullptr, nullptr, normf_W, out,
        MROWS, FEAT, D_MODEL, D_MODEL, 0, FEAT, D_MODEL);
}